// Round 6
// baseline (3217.031 us; speedup 1.0000x reference)
//
#include <hip/hip_runtime.h>

#define DIMD 256
#define SEQT 1024
#define NB   4
#define KBS  20        // 16-row block + 4 pad: 16B-aligned bases, <=2-way bank alias (free)

typedef float v2f __attribute__((ext_vector_type(2)));
#define FMA2(a,b,c) __builtin_elementwise_fma((a),(b),(c))

__device__ __forceinline__ float sigmoidf_(float x){ return 1.0f/(1.0f+expf(-x)); }

__device__ __forceinline__ v2f shfl_xor_v2(v2f v, int m){
  v2f r; r.x = __shfl_xor(v.x, m, 64); r.y = __shfl_xor(v.y, m, 64); return r;
}

// ---------------------------------------------------------------------------
// GEMM: C[m][n] = sum_k A[m][k] * B[n][k], K = 256 fixed, tiles 64x64.
// EPI==1: C *= sigmoid(gpre[m*N+n])
// ---------------------------------------------------------------------------
template<int EPI>
__global__ __launch_bounds__(256) void gemm_bt(const float* __restrict__ A,
    const float* __restrict__ Bm, float* __restrict__ C, int N,
    const float* __restrict__ gpre)
{
  __shared__ float sA[64][68];
  __shared__ float sB[64][68];
  const int nb = N >> 6;
  const int bm = blockIdx.x / nb, bn = blockIdx.x - bm*nb;
  const int m0 = bm << 6, n0 = bn << 6;
  const int tid = threadIdx.x;
  const int tr = tid >> 4, tc = tid & 15;
  float acc[4][4];
  #pragma unroll
  for (int i=0;i<4;i++)
    #pragma unroll
    for (int j=0;j<4;j++) acc[i][j]=0.f;

  for (int kc=0;kc<4;kc++){
    __syncthreads();
    for (int i=tid;i<1024;i+=256){
      int r = i >> 4, q4 = i & 15;
      *(float4*)&sA[r][q4*4] = ((const float4*)(A  + (m0+r)*256 + kc*64))[q4];
      *(float4*)&sB[r][q4*4] = ((const float4*)(Bm + (n0+r)*256 + kc*64))[q4];
    }
    __syncthreads();
    #pragma unroll
    for (int kq=0;kq<16;kq++){
      float4 av[4], bv[4];
      #pragma unroll
      for (int i=0;i<4;i++) av[i] = *(const float4*)&sA[tr+16*i][kq*4];
      #pragma unroll
      for (int j=0;j<4;j++) bv[j] = *(const float4*)&sB[tc+16*j][kq*4];
      #pragma unroll
      for (int i=0;i<4;i++)
        #pragma unroll
        for (int j=0;j<4;j++)
          acc[i][j] = fmaf(av[i].x,bv[j].x, fmaf(av[i].y,bv[j].y,
                      fmaf(av[i].z,bv[j].z, fmaf(av[i].w,bv[j].w, acc[i][j]))));
    }
  }
  #pragma unroll
  for (int i=0;i<4;i++){
    #pragma unroll
    for (int j=0;j<4;j++){
      int m = m0 + tr + 16*i, n = n0 + tc + 16*j;
      float val = acc[i][j];
      if (EPI==1) val *= sigmoidf_(gpre[m*N+n]);
      C[m*N+n] = val;
    }
  }
}

// ---------------------------------------------------------------------------
// prep: causal dwconv(4) + RoPE + l2norm for q,k ; conv for v ; eta/alpha.
// ---------------------------------------------------------------------------
__global__ __launch_bounds__(256) void prep_kernel(
    const float* __restrict__ qkvr, const float* __restrict__ x,
    const float* __restrict__ cosT, const float* __restrict__ sinT,
    const float* __restrict__ qw, const float* __restrict__ qbias,
    const float* __restrict__ kw, const float* __restrict__ kbias,
    const float* __restrict__ vw, const float* __restrict__ vbias,
    const float* __restrict__ Wparam, const float* __restrict__ bparam,
    float* __restrict__ qo, float* __restrict__ ko, float* __restrict__ vo,
    float* __restrict__ eo, float* __restrict__ ao)
{
  const int bt = blockIdx.x;
  const int t = bt & 1023;
  const int d = threadIdx.x;

  float4 wq = ((const float4*)qw)[d];
  float4 wk = ((const float4*)kw)[d];
  float4 wv = ((const float4*)vw)[d];
  const float wqj[4] = {wq.x,wq.y,wq.z,wq.w};
  const float wkj[4] = {wk.x,wk.y,wk.z,wk.w};
  const float wvj[4] = {wv.x,wv.y,wv.z,wv.w};
  float qa = qbias[d], ka = kbias[d], va = vbias[d];
  #pragma unroll
  for (int j=0;j<4;j++){
    int tt = t - 3 + j;
    if (tt >= 0) {
      const float* row = qkvr + (size_t)(bt - 3 + j) * 768;
      qa = fmaf(row[d],      wqj[j], qa);
      ka = fmaf(row[256+d],  wkj[j], ka);
      va = fmaf(row[512+d],  wvj[j], va);
    }
  }
  vo[bt*256 + d] = va;

  __shared__ float sq[256], sk[256];
  __shared__ float red[4][4];
  sq[d] = qa; sk[d] = ka;
  __syncthreads();
  const int i = d >> 1;
  const float c = cosT[t*128 + i], s = sinT[t*128 + i];
  float qr, krp;
  if ((d & 1) == 0) { qr = sq[d]*c - sq[d+1]*s;  krp = sk[d]*c - sk[d+1]*s; }
  else              { qr = sq[d-1]*s + sq[d]*c;  krp = sk[d-1]*s + sk[d]*c; }

  const float xd = x[bt*256 + d];
  float r0 = qr*qr, r1 = krp*krp, r2 = xd*Wparam[d], r3 = xd*Wparam[256+d];
  #pragma unroll
  for (int m=1;m<64;m<<=1){
    r0 += __shfl_xor(r0, m, 64);
    r1 += __shfl_xor(r1, m, 64);
    r2 += __shfl_xor(r2, m, 64);
    r3 += __shfl_xor(r3, m, 64);
  }
  const int w = d >> 6;
  if ((d & 63) == 0){ red[w][0]=r0; red[w][1]=r1; red[w][2]=r2; red[w][3]=r3; }
  __syncthreads();
  float qss = red[0][0]+red[1][0]+red[2][0]+red[3][0];
  float kss = red[0][1]+red[1][1]+red[2][1]+red[3][1];
  qo[bt*256+d] = qr  / fmaxf(sqrtf(qss), 1e-12f);
  ko[bt*256+d] = krp / fmaxf(sqrtf(kss), 1e-12f);
  if (d == 0){
    float p0 = red[0][2]+red[1][2]+red[2][2]+red[3][2] + bparam[0];
    float p1 = red[0][3]+red[1][3]+red[2][3]+red[3][3] + bparam[1];
    eo[bt] = 1.f/(1.f+expf(-p0));
    ao[bt] = 1.f/(1.f+expf(-p1));
  }
}

// ---------------------------------------------------------------------------
// scan: one block per batch, 1024 threads (4 waves/SIMD), ONE barrier/step.
// Thread (rg=tid&15, cg=tid>>4) owns A[16*rg .. 16*rg+15][4*cg .. 4*cg+3]
// as 32 v2f regs. Each k/q value serves 4 columns in registers -> LDS reads
// drop to 12 b128/thread/step (was 48). Next step's k-dot (pred_raw) is
// fused into the update loop against k(t+1), which is already staged in the
// next buffer. Cross-rg reduces are intra-wave (xor 1,2,4,8). k/q LDS tiles
// use KBS=20 row-blocks: 16B-aligned, worst 2-way bank alias (free, m136).
// Triple-buffered k/q/v/ea: barrier(t) separates fused(t-1) reads of
// buf[(t-1)%3] from stage(t+1) writes to that same buffer.
// ---------------------------------------------------------------------------
__global__ __launch_bounds__(1024, 4) void scan_kernel(
    const float* __restrict__ qn, const float* __restrict__ kn,
    const float* __restrict__ vn, const float* __restrict__ eta,
    const float* __restrict__ alpha, const float* __restrict__ W0,
    float* __restrict__ y)
{
  const int b = blockIdx.x;
  const int tid = threadIdx.x;
  const int rg = tid & 15;        // row group: rows 16*rg .. 16*rg+15
  const int cg = tid >> 4;        // col group: cols 4*cg .. 4*cg+3
  const int r0 = rg << 4;
  const int c0 = cg << 2;
  const int koff = KBS * rg;      // base of this row block in s_k/s_q

  __shared__ float s_k[3][16*KBS], s_q[3][16*KBS], s_v[3][256];
  __shared__ float s_ea[3][2];
  __shared__ float s_s4[2][16];

  // A2[2*i]   = A[r0+i][{c0,  c0+1}]
  // A2[2*i+1] = A[r0+i][{c0+2,c0+3}]
  v2f A2[32];
  #pragma unroll
  for (int j=0;j<32;j++) A2[j] = (v2f)(0.f);

  const float* kb = kn + b*SEQT*DIMD;
  const float* qb = qn + b*SEQT*DIMD;
  const float* vb = vn + b*SEQT*DIMD;
  const float* eb = eta   + b*SEQT;
  const float* ab = alpha + b*SEQT;
  float* yb = y + b*SEQT*DIMD;

  // ---- prologue: stage t=0 -> buf0 ; load t=1 into pf regs
  if (tid < 64) {
    float4 v0 = ((const float4*)kb)[tid];
    *(float4*)&s_k[0][KBS*(tid>>2) + 4*(tid&3)] = v0;
  } else if (tid < 128) {
    int i = tid-64;
    float4 v0 = ((const float4*)qb)[i];
    *(float4*)&s_q[0][KBS*(i>>2) + 4*(i&3)] = v0;
  } else if (tid < 192) {
    ((float4*)s_v[0])[tid-128] = ((const float4*)vb)[tid-128];
  }
  if (tid == 192) { s_ea[0][0] = eb[0]; s_ea[0][1] = ab[0]; }

  float4 pf = make_float4(0.f,0.f,0.f,0.f);
  float pe = 0.f, pa = 0.f;
  if (tid < 64)       pf = ((const float4*)(kb + DIMD))[tid];
  else if (tid < 128) pf = ((const float4*)(qb + DIMD))[tid-64];
  else if (tid < 192) pf = ((const float4*)(vb + DIMD))[tid-128];
  if (tid == 192) { pe = eb[1]; pa = ab[1]; }
  __syncthreads();

  // ---- prologue: pred_raw(0) = k(0) . W0 (partial over own rows/cols)
  v2f pr01 = (v2f)(0.f), pr23 = (v2f)(0.f);
  {
    const float4* kp0 = (const float4*)(s_k[0] + koff);
    #pragma unroll
    for (int j=0;j<4;j++){
      float4 k4 = kp0[j];
      #pragma unroll
      for (int i=0;i<4;i++){
        float ks = ((const float*)&k4)[i];
        v2f ksv = {ks, ks};
        int r = r0 + 4*j + i;
        float4 w4 = *(const float4*)(W0 + (size_t)r*DIMD + c0);
        v2f w01 = {w4.x, w4.y}, w23 = {w4.z, w4.w};
        pr01 = FMA2(ksv, w01, pr01);
        pr23 = FMA2(ksv, w23, pr23);
      }
    }
    #pragma unroll
    for (int m=1;m<16;m<<=1){
      pr01 += shfl_xor_v2(pr01, m);
      pr23 += shfl_xor_v2(pr23, m);
    }
  }

  v2f up01 = (v2f)(0.f), up23 = (v2f)(0.f);   // u of step t-1 (y write)
  int cur = 0;

  for (int t=0; t<SEQT; ++t) {
    const int nxt = (cur==2) ? 0 : cur+1;

    // ---- stage pf (t+1 data) -> buf nxt
    if (t+1 < SEQT) {
      if (tid < 64)       *(float4*)&s_k[nxt][KBS*(tid>>2) + 4*(tid&3)] = pf;
      else if (tid < 128){ int i = tid-64; *(float4*)&s_q[nxt][KBS*(i>>2) + 4*(i&3)] = pf; }
      else if (tid < 192) ((float4*)s_v[nxt])[tid-128] = pf;
      if (tid == 192) { s_ea[nxt][0]=pe; s_ea[nxt][1]=pa; }
    }

    __syncthreads();                               // the ONE barrier

    // ---- issue global prefetch for t+2 (lands under the fused loop)
    if (t+2 < SEQT) {
      if (tid < 64)       pf = ((const float4*)(kb + (t+2)*DIMD))[tid];
      else if (tid < 128) pf = ((const float4*)(qb + (t+2)*DIMD))[tid-64];
      else if (tid < 192) pf = ((const float4*)(vb + (t+2)*DIMD))[tid-128];
      if (tid == 192) { pe = eb[t+2]; pa = ab[t+2]; }
    }

    // ---- inv(t-1) from s4 partials ; deferred y(t-1) write
    float scale = 1.f;
    if (t > 0) {
      const float* sp = s_s4[(t-1)&1];
      float4 sa = ((const float4*)sp)[0], sb4 = ((const float4*)sp)[1];
      float4 sc4= ((const float4*)sp)[2], sd4 = ((const float4*)sp)[3];
      float s4t = ((sa.x+sa.y)+(sa.z+sa.w)) + ((sb4.x+sb4.y)+(sb4.z+sb4.w))
                + ((sc4.x+sc4.y)+(sc4.z+sc4.w)) + ((sd4.x+sd4.y)+(sd4.z+sd4.w));
      float w = sqrtf(s4t) + 1e-6f;
      float r = __builtin_amdgcn_rcpf(w);
      r = r * (2.f - w*r);          // Newton: feeds the recurrence
      scale = r;
      if (rg == 0) {
        float4 yo = make_float4(up01.x*r, up01.y*r, up23.x*r, up23.y*r);
        *(float4*)(yb + (size_t)(t-1)*DIMD + c0) = yo;
      }
    }

    // ---- pred -> t0 per column
    v2f pred01 = pr01 * scale, pred23 = pr23 * scale;
    const float et = s_ea[cur][0], al = s_ea[cur][1];
    float4 v4 = *(const float4*)(s_v[cur] + c0);
    v2f df01 = pred01 - (v2f){v4.x, v4.y};
    v2f df23 = pred23 - (v2f){v4.z, v4.w};
    // tanh(10*df) = 1 - 2/(exp(20*df)+1)
    float e0 = __expf(20.f*df01.x), e1 = __expf(20.f*df01.y);
    float e2 = __expf(20.f*df23.x), e3 = __expf(20.f*df23.y);
    v2f th01 = { 1.f - 2.f*__builtin_amdgcn_rcpf(e0+1.f),
                 1.f - 2.f*__builtin_amdgcn_rcpf(e1+1.f) };
    v2f th23 = { 1.f - 2.f*__builtin_amdgcn_rcpf(e2+1.f),
                 1.f - 2.f*__builtin_amdgcn_rcpf(e3+1.f) };
    const v2f etv = {et, et}, c3 = {3.f, 3.f};
    v2f t0v01 = etv * c3 * th01 * (df01*df01);
    v2f t0v23 = etv * c3 * th23 * (df23*df23);
    const v2f alv = {al, al};

    // ---- fused: A update + sumA^4 + q-dot + NEXT k-dot, one pass over A
    v2f s4a = (v2f)(0.f), s4b = (v2f)(0.f);
    v2f u01 = (v2f)(0.f), u23 = (v2f)(0.f);
    v2f p01 = (v2f)(0.f), p23 = (v2f)(0.f);
    {
      const float4* kp = (const float4*)(s_k[cur] + koff);
      const float4* qp = (const float4*)(s_q[cur] + koff);
      const float4* np = (const float4*)(s_k[nxt] + koff);   // k(t+1)
      #pragma unroll
      for (int j=0;j<4;j++){
        float4 k4 = kp[j], q4 = qp[j], n4 = np[j];
        #pragma unroll
        for (int i=0;i<4;i++){
          float ks = ((const float*)&k4)[i];
          float qs = ((const float*)&q4)[i];
          float ns = ((const float*)&n4)[i];
          v2f ksv = {ks,ks}, qsv = {qs,qs}, nsv = {ns,ns};
          const int idx = 2*(4*j+i);
          v2f a01 = FMA2(alv, A2[idx],   -(t0v01*ksv)); A2[idx]   = a01;
          v2f a23 = FMA2(alv, A2[idx+1], -(t0v23*ksv)); A2[idx+1] = a23;
          v2f sq01 = a01*a01, sq23 = a23*a23;
          s4a = FMA2(sq01, sq01, s4a);
          s4b = FMA2(sq23, sq23, s4b);
          u01 = FMA2(qsv, a01, u01);
          u23 = FMA2(qsv, a23, u23);
          p01 = FMA2(nsv, a01, p01);
          p23 = FMA2(nsv, a23, p23);
        }
      }
    }

    // ---- intra-wave cross-rg reduces (lanes xor 1,2,4,8 share columns)
    #pragma unroll
    for (int m=1;m<16;m<<=1){
      p01 += shfl_xor_v2(p01, m);
      p23 += shfl_xor_v2(p23, m);
      u01 += shfl_xor_v2(u01, m);
      u23 += shfl_xor_v2(u23, m);
    }
    pr01 = p01; pr23 = p23;
    up01 = u01; up23 = u23;

    // ---- s4 wave reduce -> per-wave slot (consumed next step post-barrier)
    float s4 = (s4a.x + s4a.y) + (s4b.x + s4b.y);
    #pragma unroll
    for (int m=1;m<64;m<<=1) s4 += __shfl_xor(s4, m, 64);
    if ((tid & 63) == 0) s_s4[t&1][tid>>6] = s4;

    cur = nxt;
  }

  __syncthreads();
  // epilogue: y for t = 1023 (s4 in s_s4[1023&1 = 1])
  {
    const float* sp = s_s4[1];
    float4 sa = ((const float4*)sp)[0], sb4 = ((const float4*)sp)[1];
    float4 sc4= ((const float4*)sp)[2], sd4 = ((const float4*)sp)[3];
    float s4t = ((sa.x+sa.y)+(sa.z+sa.w)) + ((sb4.x+sb4.y)+(sb4.z+sb4.w))
              + ((sc4.x+sc4.y)+(sc4.z+sc4.w)) + ((sd4.x+sd4.y)+(sd4.z+sd4.w));
    float w = sqrtf(s4t) + 1e-6f;
    float r = __builtin_amdgcn_rcpf(w);
    r = r * (2.f - w*r);
    if (rg == 0) {
      float4 yo = make_float4(up01.x*r, up01.y*r, up23.x*r, up23.y*r);
      *(float4*)(yb + (size_t)1023*DIMD + c0) = yo;
    }
  }
}

// ---------------------------------------------------------------------------
extern "C" void kernel_launch(void* const* d_in, const int* in_sizes, int n_in,
                              void* d_out, int out_size, void* d_ws, size_t ws_size,
                              hipStream_t stream)
{
  const float* x     = (const float*)d_in[0];
  const float* cosT  = (const float*)d_in[1];
  const float* sinT  = (const float*)d_in[2];
  const float* Wqkv  = (const float*)d_in[3];
  const float* qw    = (const float*)d_in[4];
  const float* qb    = (const float*)d_in[5];
  const float* kw    = (const float*)d_in[6];
  const float* kb    = (const float*)d_in[7];
  const float* vw    = (const float*)d_in[8];
  const float* vb    = (const float*)d_in[9];
  const float* Wparam= (const float*)d_in[10];
  const float* bparam= (const float*)d_in[11];
  const float* W0    = (const float*)d_in[12];
  const float* Wgate = (const float*)d_in[13];
  const float* Wout  = (const float*)d_in[14];
  float* out = (float*)d_out;

  float* ws    = (float*)d_ws;
  float* qkvr  = ws;                         // 4*1024*768  = 3,145,728 f
  float* qn    = qkvr + 4*1024*768;          // 1,048,576 f
  float* kn    = qn   + 4*1024*256;
  float* vn    = kn   + 4*1024*256;
  float* eta   = vn   + 4*1024*256;          // 4096 f
  float* alpha = eta  + 4096;                // 4096 f
  // qkvr is dead after prep_kernel -> reuse its space:
  float* yv    = qkvr;                       // scan output  (1,048,576 f)
  float* tmpg  = qkvr + 1048576;             // gate preact  (1,048,576 f)

  // 1) qkv = x @ Wqkv.T          (4096 x 768)
  gemm_bt<0><<<dim3(64*12), 256, 0, stream>>>(x, Wqkv, qkvr, 768, nullptr);
  // 2) conv + rope + l2norm + eta/alpha
  prep_kernel<<<dim3(4096), 256, 0, stream>>>(qkvr, x, cosT, sinT,
      qw, qb, kw, kb, vw, vb, Wparam, bparam, qn, kn, vn, eta, alpha);
  // 3) the sequential scan (one block per batch)
  scan_kernel<<<dim3(NB), 1024, 0, stream>>>(qn, kn, vn, eta, alpha, W0, yv);
  // 4) gate preact = x @ Wgate.T (4096 x 256)
  gemm_bt<0><<<dim3(64*4), 256, 0, stream>>>(x, Wgate, tmpg, 256, nullptr);
  // 5) out = (y @ Wout.T) * sigmoid(gate)
  gemm_bt<1><<<dim3(64*4), 256, 0, stream>>>(yv, Wout, out, 256, tmpg);
}